// Round 2
// baseline (451.377 us; speedup 1.0000x reference)
//
#include <hip/hip_runtime.h>
#include <cstdint>
#include <cstddef>

#define GK0 0.7978845608028654f
#define GC1 0.044715f

typedef __attribute__((ext_vector_type(8))) short short8;
typedef __attribute__((ext_vector_type(4))) float floatx4;

__device__ __forceinline__ unsigned short f2bf(float f) {
  union { float f; unsigned int u; } v; v.f = f;
  unsigned int r = v.u + 0x7fffu + ((v.u >> 16) & 1u);   // RNE
  return (unsigned short)(r >> 16);
}

// async 16B global->LDS (LDS dest = wave-uniform base + lane*16; global src per-lane)
__device__ __forceinline__ void gl_lds16(const unsigned short* g, unsigned short* l) {
  __builtin_amdgcn_global_load_lds(
      (const __attribute__((address_space(1))) unsigned int*)g,
      (__attribute__((address_space(3))) unsigned int*)l, 16, 0, 0);
}

// ---- weights: [co][ci][3][3] f32 -> wt[khw][co][ci] bf16; also zero out ----
__global__ void k_wt(const float* __restrict__ w, unsigned short* __restrict__ wt,
                     float* __restrict__ out) {
  if (blockIdx.x == 0) {
    for (int i = threadIdx.x; i < 32 * 128; i += 256) out[i] = 0.0f;
  }
  int t = blockIdx.x * 256 + threadIdx.x;
  if (t >= 128 * 64 * 9) return;
  int co = t / 576; int r = t - co * 576; int ci = r / 9; int khw = r - ci * 9;
  wt[(khw * 128 + co) * 64 + ci] = f2bf(w[t]);
}

// ---- phase 1: NCHW fp32 -> NHWC bf16  xb[b][h][w][ci] ---- (unchanged from R1)
__global__ __launch_bounds__(256) void k_xt(const float* __restrict__ x,
                                            unsigned short* __restrict__ xb) {
  __shared__ float tile[64 * 132];
  const int tid = threadIdx.x, lane = tid & 63, wv = tid >> 6;
  const int b = blockIdx.y, h = blockIdx.x;
  const int w4 = lane & 31, cih = lane >> 5;

#pragma unroll
  for (int j = 0; j < 8; j++) {                        // load 64ci x 128w fp32
    const int ci = wv * 16 + 2 * j + cih;
    float4 f = *(const float4*)(x + ((size_t)(b * 64 + ci) * 128 + h) * 128 + 4 * w4);
    *(float4*)((char*)tile + ci * 528 + ((16 * w4) ^ (((ci >> 3) & 7) << 4))) = f;
  }
  __syncthreads();
  unsigned short* orow = xb + ((size_t)b * 128 + h) * 8192;
  const int oct = tid & 7, wlo = tid >> 3;
#pragma unroll
  for (int it = 0; it < 4; it++) {
    const int w = wlo + 32 * it;
    short8 v;
#pragma unroll
    for (int j = 0; j < 8; j++) {
      const float f =
          *(const float*)((const char*)tile + (8 * oct + j) * 528 + ((4 * w) ^ (oct << 4)));
      v[j] = (short)f2bf(f);
    }
    *(short8*)(orow + w * 64 + oct * 8) = v;           // 16B/lane, contiguous
  }
}

// ---- phase 2: implicit-GEMM conv + fused bias/GELU/pool ----
// grid (2 w-halves, 63 h-pairs, 32 b), block 256 (4 waves), wave tile 64co x 64pos.
// A (weights): global->VGPR, hoisted to TOP of each kh step (24 short8, all
// compile-time indexed) so the A s_waitcnt is vmcnt(18) and the 18-load B-prefetch
// stays in flight across the whole compute phase (fixes R1's vmcnt poisoning).
// Weights are 144 KB, identical addresses for all waves/blocks -> L1-resident.
// B: kh-merged (one 72-pos row pair serves all 3 kw), double-buffered LDS,
// XOR-swizzled (pre-swizzled global source; conflicts measured 0). 3 barriers total.
__global__ __launch_bounds__(256, 2) void k_conv(
    const unsigned short* __restrict__ xb, const unsigned short* __restrict__ wt,
    const float* __restrict__ bias, float* __restrict__ out) {
  __shared__ __align__(16) unsigned short Bs[2][9216];  // [buf][rh(2)][pos(72)][ci(64)]
  const int tid = threadIdx.x, lane = tid & 63, wv = tid >> 6;
  const int w0 = blockIdx.x * 64, h0 = blockIdx.y * 2, b = blockIdx.z;
  const int wm = wv & 1, wn = wv >> 1;                  // co-half, h-row
  const int m = lane & 15, q = lane >> 4;
  // stage source pre-swizzle: LDS slot l&7 of subrow l>>3 gets source slot (l&7)^(l>>3)
  const int swz = ((lane >> 3) << 6) + (((lane & 7) ^ (lane >> 3)) << 3);

  floatx4 acc[4][4];
#pragma unroll
  for (int i = 0; i < 4; i++)
#pragma unroll
    for (int j = 0; j < 4; j++) acc[i][j] = (floatx4){0.f, 0.f, 0.f, 0.f};

  const unsigned short* xbb = xb + (size_t)b * 128 * 8192;

  auto stage = [&](unsigned short* bs, int row0) {
    for (int c = wv; c < 18; c += 4) {                  // 18 x 1KB chunks
      const int rh = (c >= 9) ? 1 : 0;
      const int j = c - 9 * rh;
      gl_lds16(xbb + ((size_t)((row0 + rh) * 128 + w0) << 6) + j * 512 + swz,
               bs + rh * 4608 + j * 512);
    }
  };

  stage(Bs[0], h0);
  __syncthreads();

#pragma unroll
  for (int kh = 0; kh < 3; kh++) {
    // 1) A-loads FIRST (oldest vmem ops of this step): 2 half x 3 kw x 4 mt
    short8 a[2][3][4];
#pragma unroll
    for (int half = 0; half < 2; half++)
#pragma unroll
      for (int kw = 0; kw < 3; kw++)
#pragma unroll
        for (int mt = 0; mt < 4; mt++)
          a[half][kw][mt] = *(const short8*)(wt + (kh * 3 + kw) * 8192 +
                                             (wm * 64 + mt * 16 + m) * 64 +
                                             half * 32 + q * 8);
    // 2) B-prefetch for kh+1 (newest vmem ops -> A-waits never drain these)
    if (kh < 2) stage(Bs[(kh + 1) & 1], h0 + kh + 1);
    // 3) compute from Bs[kh&1]
    const unsigned short* bsr = Bs[kh & 1] + wn * 4608;
#pragma unroll
    for (int half = 0; half < 2; half++) {
      const int colb = half * 32 + q * 8;
#pragma unroll
      for (int kw = 0; kw < 3; kw++) {
        const int xr = ((m + kw) & 7) << 3;             // read-side un-swizzle
        short8 bf[4];
#pragma unroll
        for (int nt = 0; nt < 4; nt++)
          bf[nt] = *(const short8*)(bsr + (nt * 16 + m + kw) * 64 + (colb ^ xr));
#pragma unroll
        for (int mt = 0; mt < 4; mt++)
#pragma unroll
          for (int nt = 0; nt < 4; nt++)
            acc[mt][nt] = __builtin_amdgcn_mfma_f32_16x16x32_bf16(
                a[half][kw][mt], bf[nt], acc[mt][nt], 0, 0, 0);
      }
    }
    __syncthreads();                                    // buffer swap; drains stage
  }

  // epilogue: bias + fast tanh-GELU (y*sigmoid(2u)) + masked pool
  // D layout: col n = wn*64 + nt*16 + (lane&15) -> w' = nt*16+m; row co = q*4+r
  const float inv_area = 1.0f / (126.0f * 126.0f);
  float* orow = out + b * 128;
#pragma unroll
  for (int mt = 0; mt < 4; mt++)
#pragma unroll
    for (int r2 = 0; r2 < 4; r2++) {
      const int co = wm * 64 + mt * 16 + q * 4 + r2;
      const float bv = bias[co];
      float s = 0.f;
#pragma unroll
      for (int nt = 0; nt < 4; nt++) {
        float y = acc[mt][nt][r2] + bv;
        float u = GK0 * (y + GC1 * y * y * y);
        float e = __expf(-2.0f * u);
        float g = y * __builtin_amdgcn_rcpf(1.0f + e);  // == 0.5y(1+tanh u)
        if (w0 + nt * 16 + m < 126) s += g;             // mask padded w' = 126,127
      }
#pragma unroll
      for (int d = 1; d < 16; d <<= 1) s += __shfl_xor(s, d, 64);
      if (m == 0) atomicAdd(&orow[co], s * inv_area);
    }
}

extern "C" void kernel_launch(void* const* d_in, const int* in_sizes, int n_in,
                              void* d_out, int out_size, void* d_ws, size_t ws_size,
                              hipStream_t stream) {
  const float* x    = (const float*)d_in[0];
  const float* w    = (const float*)d_in[1];
  const float* bias = (const float*)d_in[2];
  float* out = (float*)d_out;

  const size_t xb_elems = (size_t)32 * 128 * 8192;      // 64 MiB bf16 NHWC
  unsigned short* xbuf = (unsigned short*)d_ws;
  unsigned short* wbuf = xbuf + xb_elems + 2048;        // 4 KB slack (B halo overreads)
  if (ws_size < xb_elems * 2 + 4096 + (size_t)9 * 128 * 64 * 2) return;

  k_wt<<<288, 256, 0, stream>>>(w, wbuf, out);
  k_xt<<<dim3(128, 32), 256, 0, stream>>>(x, xbuf);
  k_conv<<<dim3(2, 63, 32), 256, 0, stream>>>(xbuf, wbuf, bias, out);
}

// Round 3
// 400.731 us; speedup vs baseline: 1.1264x; 1.1264x over previous
//
#include <hip/hip_runtime.h>
#include <cstdint>
#include <cstddef>

#define GK0 0.7978845608028654f
#define GC1 0.044715f

typedef __attribute__((ext_vector_type(8))) short short8;
typedef __attribute__((ext_vector_type(4))) float floatx4;

__device__ __forceinline__ unsigned short f2bf(float f) {
  union { float f; unsigned int u; } v; v.f = f;
  unsigned int r = v.u + 0x7fffu + ((v.u >> 16) & 1u);   // RNE
  return (unsigned short)(r >> 16);
}

// async 16B global->LDS (LDS dest = wave-uniform base + lane*16; global src per-lane)
__device__ __forceinline__ void gl_lds16(const unsigned short* g, unsigned short* l) {
  __builtin_amdgcn_global_load_lds(
      (const __attribute__((address_space(1))) unsigned int*)g,
      (__attribute__((address_space(3))) unsigned int*)l, 16, 0, 0);
}

// ---- weights: [co][ci][3][3] f32 -> wt[khw][co][ci] bf16; also zero out ----
__global__ void k_wt(const float* __restrict__ w, unsigned short* __restrict__ wt,
                     float* __restrict__ out) {
  if (blockIdx.x == 0) {
    for (int i = threadIdx.x; i < 32 * 128; i += 256) out[i] = 0.0f;
  }
  int t = blockIdx.x * 256 + threadIdx.x;
  if (t >= 128 * 64 * 9) return;
  int co = t / 576; int r = t - co * 576; int ci = r / 9; int khw = r - ci * 9;
  wt[(khw * 128 + co) * 64 + ci] = f2bf(w[t]);
}

// ---- single-pass implicit-GEMM conv + fused transpose/bias/GELU/pool ----
// grid (2 w-halves, 63 h-pairs, 32 b), block 256 (4 waves), wave tile 64co x 64pos.
// No xb intermediate: block stages its 4 input rows (f32 NCHW -> bf16 [pos][ci],
// XOR-swizzled) ONCE into LDS; those 36 KB serve all 9 taps. A (weights) is
// double-buffered 16 KB LDS via global_load_lds with pre-swizzled source (conflict-
// free, proven R1/R2); stage of tap k+1 issues before compute of tap k, so the
// per-tap barrier drains loads issued a full compute phase earlier. Zero global
// loads in the compute phase (R1/R2 showed compiler can't schedule those well).
__global__ __launch_bounds__(256, 2) void k_conv(
    const float* __restrict__ x, const unsigned short* __restrict__ wt,
    const float* __restrict__ bias, float* __restrict__ out) {
  __shared__ __align__(16) unsigned short Bs[4 * 72 * 64];   // 36,864 B [r][p(72)][ci]
  __shared__ __align__(16) unsigned short As[2][8192];       // 2 x 16 KB [co][ci] dbuf
  const int tid = threadIdx.x, lane = tid & 63, wv = tid >> 6;
  const int w0 = blockIdx.x * 64, h0 = blockIdx.y * 2, b = blockIdx.z;
  const int wm = wv & 1, wn = wv >> 1;                       // co-half, h-row
  const int m = lane & 15, q = lane >> 4;

  floatx4 acc[4][4];
#pragma unroll
  for (int i = 0; i < 4; i++)
#pragma unroll
    for (int j = 0; j < 4; j++) acc[i][j] = (floatx4){0.f, 0.f, 0.f, 0.f};

  // ---- B prologue: 4 input rows, f32 coalesced loads -> cvt -> swizzled LDS ----
  // LDS elem (r, p, c') holds input[r][p][c' ^ ((p&7)<<3)]  (read-compatible XOR)
  for (int r = 0; r < 4; r++) {
    const float* xrow = x + ((size_t)(b * 64) * 128 + (h0 + r)) * 128;
    unsigned short* brow = Bs + r * 4608;
    for (int c = tid; c < 1152; c += 256) {                  // 64ci x 18 float4-chunks
      const int ci = c / 18, i = c - ci * 18;
      const int wc = min(w0 + 4 * i, 124);                   // clamp: dup data only
      union { float4 v; float f[4]; } u;                     // feeds masked outputs
      u.v = *(const float4*)(xrow + (size_t)ci * 16384 + wc);
#pragma unroll
      for (int k2 = 0; k2 < 4; k2++) {
        const int p = 4 * i + k2;                            // staged slot index
        brow[p * 64 + (ci ^ ((p & 7) << 3))] = f2bf(u.f[k2]);
      }
    }
  }

  // ---- A stage: 16 chunks x 8 co-rows; source pre-swizzled so linear LDS dest
  // ends up with row-XOR layout: LDS (row, cg) = wt[row][cg ^ (row&7)] ----
  auto stageA = [&](unsigned short* dst, int khw) {
    const unsigned short* src = wt + khw * 8192;
#pragma unroll
    for (int i = 0; i < 4; i++) {
      const int chunk = wv * 4 + i;
      gl_lds16(src + chunk * 512 + (lane >> 3) * 64 + (((lane & 7) ^ (lane >> 3)) << 3),
               dst + chunk * 512);
    }
  };

  stageA(As[0], 0);
  __syncthreads();                                           // B visible, A0 ready

#pragma unroll
  for (int kh = 0; kh < 3; kh++)
#pragma unroll
    for (int kw = 0; kw < 3; kw++) {
      const int khw = kh * 3 + kw;
      if (khw < 8) stageA(As[(khw + 1) & 1], khw + 1);       // prefetch next tap
      const unsigned short* acur = As[khw & 1] + wm * 4096;
      const unsigned short* bcur = Bs + (wn + kh) * 4608;
#pragma unroll
      for (int half = 0; half < 2; half++) {
        const int colb = half * 32 + q * 8;
        short8 a[4], bf[4];
#pragma unroll
        for (int mt = 0; mt < 4; mt++)
          a[mt] = *(const short8*)(acur + (mt * 16 + m) * 64 + (colb ^ ((m & 7) << 3)));
#pragma unroll
        for (int nt = 0; nt < 4; nt++)
          bf[nt] = *(const short8*)(bcur + (nt * 16 + m + kw) * 64 +
                                    (colb ^ (((m + kw) & 7) << 3)));
#pragma unroll
        for (int mt = 0; mt < 4; mt++)
#pragma unroll
          for (int nt = 0; nt < 4; nt++)
            acc[mt][nt] = __builtin_amdgcn_mfma_f32_16x16x32_bf16(
                a[mt], bf[nt], acc[mt][nt], 0, 0, 0);
      }
      __syncthreads();                                       // A-buffer swap fence
    }

  // epilogue: bias + fast tanh-GELU (y*sigmoid(2u)) + masked pool
  // D layout: col n = wn*64 + nt*16 + (lane&15) -> w' = nt*16+m; row co = q*4+r
  const float inv_area = 1.0f / (126.0f * 126.0f);
  float* orow = out + b * 128;
#pragma unroll
  for (int mt = 0; mt < 4; mt++)
#pragma unroll
    for (int r2 = 0; r2 < 4; r2++) {
      const int co = wm * 64 + mt * 16 + q * 4 + r2;
      const float bv = bias[co];
      float s = 0.f;
#pragma unroll
      for (int nt = 0; nt < 4; nt++) {
        float y = acc[mt][nt][r2] + bv;
        float u = GK0 * (y + GC1 * y * y * y);
        float e = __expf(-2.0f * u);
        float g = y * __builtin_amdgcn_rcpf(1.0f + e);       // == 0.5y(1+tanh u)
        if (w0 + nt * 16 + m < 126) s += g;                  // mask padded w'
      }
#pragma unroll
      for (int d = 1; d < 16; d <<= 1) s += __shfl_xor(s, d, 64);
      if (m == 0) atomicAdd(&orow[co], s * inv_area);
    }
}

extern "C" void kernel_launch(void* const* d_in, const int* in_sizes, int n_in,
                              void* d_out, int out_size, void* d_ws, size_t ws_size,
                              hipStream_t stream) {
  const float* x    = (const float*)d_in[0];
  const float* w    = (const float*)d_in[1];
  const float* bias = (const float*)d_in[2];
  float* out = (float*)d_out;

  unsigned short* wbuf = (unsigned short*)d_ws;              // 144 KB weights only
  if (ws_size < (size_t)9 * 128 * 64 * 2 + 4096) return;

  k_wt<<<288, 256, 0, stream>>>(w, wbuf, out);
  k_conv<<<dim3(2, 63, 32), 256, 0, stream>>>(x, wbuf, bias, out);
}

// Round 4
// 369.423 us; speedup vs baseline: 1.2218x; 1.0847x over previous
//
#include <hip/hip_runtime.h>
#include <cstdint>
#include <cstddef>

#define GK0 0.7978845608028654f
#define GC1 0.044715f

typedef __attribute__((ext_vector_type(8))) short short8;
typedef __attribute__((ext_vector_type(4))) float floatx4;

__device__ __forceinline__ unsigned short f2bf(float f) {
  union { float f; unsigned int u; } v; v.f = f;
  unsigned int r = v.u + 0x7fffu + ((v.u >> 16) & 1u);   // RNE
  return (unsigned short)(r >> 16);
}

// async 16B global->LDS (LDS dest = wave-uniform base + lane*16; global src per-lane)
__device__ __forceinline__ void gl_lds16(const unsigned short* g, unsigned short* l) {
  __builtin_amdgcn_global_load_lds(
      (const __attribute__((address_space(1))) unsigned int*)g,
      (__attribute__((address_space(3))) unsigned int*)l, 16, 0, 0);
}

// ---- weights: [co][ci][3][3] f32 -> wt[khw][co][ci] bf16; also zero out ----
__global__ void k_wt(const float* __restrict__ w, unsigned short* __restrict__ wt,
                     float* __restrict__ out) {
  if (blockIdx.x == 0) {
    for (int i = threadIdx.x; i < 32 * 128; i += 256) out[i] = 0.0f;
  }
  int t = blockIdx.x * 256 + threadIdx.x;
  if (t >= 128 * 64 * 9) return;
  int co = t / 576; int r = t - co * 576; int ci = r / 9; int khw = r - ci * 9;
  wt[(khw * 128 + co) * 64 + ci] = f2bf(w[t]);
}

// ---- single-pass implicit-GEMM conv + fused transpose/bias/GELU/pool ----
// grid (2 w-halves, 63 h-pairs, 32 b), block 256 (4 waves), wave tile 64co x 64pos.
// BARRIER-FREE main loop (1 barrier/block, was 18): B staged once (read-only after
// prologue); A is per-WAVE-private 8 KB (own co-half), staged per tap by its own
// wave via gl_lds16 + own-wave vmcnt(0) -- no cross-wave coupling. Per tap: issue
// all 16 ds_reads -> lgkmcnt(0) (buffer dead) -> issue stage(t+1) -> 32 MFMA
// (~620 cyc, covers L2 latency of the stage) -> vmcnt(0). Prologue loads batched
// 6-deep (R3's tid-dependent loop serialized 18 x ~900cyc load-use chains).
__global__ __launch_bounds__(256, 2) void k_conv(
    const float* __restrict__ x, const unsigned short* __restrict__ wt,
    const float* __restrict__ bias, float* __restrict__ out) {
  __shared__ __align__(16) unsigned short Bs[4 * 72 * 64];   // 36,864 B [r][p(72)][ci]
  __shared__ __align__(16) unsigned short As[4][4096];       // 4 waves x 8 KB private
  const int tid = threadIdx.x, lane = tid & 63, wv = tid >> 6;
  const int w0 = blockIdx.x * 64, h0 = blockIdx.y * 2, b = blockIdx.z;
  const int wm = wv & 1, wn = wv >> 1;                       // co-half, h-row
  const int m = lane & 15, q = lane >> 4;
  unsigned short* Asw = As[wv];

  // stage-source pre-swizzle: LDS (row, g) ends up holding wt[row][g ^ (row&7)]
  const int srcswz = (lane >> 3) * 64 + (((lane & 7) ^ (lane >> 3)) << 3);
  auto stageA = [&](int khw) {                               // own co-half: 8 KB
    const unsigned short* src = wt + khw * 8192 + wm * 4096 + srcswz;
#pragma unroll
    for (int c = 0; c < 8; c++) gl_lds16(src + c * 512, Asw + c * 512);
  };

  floatx4 acc[4][4];
#pragma unroll
  for (int i = 0; i < 4; i++)
#pragma unroll
    for (int j = 0; j < 4; j++) acc[i][j] = (floatx4){0.f, 0.f, 0.f, 0.f};

  stageA(0);                                                 // lands under prologue

  // ---- B prologue: 4608 float4 chunks flat = exactly 18/thread, 3 batches of 6
  // independent loads issued before any use (breaks the serial load-use chains).
  // LDS elem (r, p, c') = input[r][p][c' ^ ((p&7)<<3)]  (read-compatible XOR).
  const float* xb0 = x + (size_t)b * 64 * 16384 + (size_t)h0 * 128;
#pragma unroll
  for (int t3 = 0; t3 < 3; t3++) {
    float4 u[6];
#pragma unroll
    for (int j = 0; j < 6; j++) {
      const int v = (t3 * 6 + j) * 256 + tid;
      const int r = v / 1152, rem = v - r * 1152;
      const int ci = rem / 18, i = rem - ci * 18;
      const int wc = min(w0 + 4 * i, 124);                   // clamp: dup data only
      u[j] = *(const float4*)(xb0 + (size_t)ci * 16384 + r * 128 + wc);  // masked out
    }
#pragma unroll
    for (int j = 0; j < 6; j++) {
      const int v = (t3 * 6 + j) * 256 + tid;
      const int r = v / 1152, rem = v - r * 1152;
      const int ci = rem / 18, i = rem - ci * 18;
      unsigned short* brow = Bs + r * 4608;
      union { float4 v4; float f[4]; } w4; w4.v4 = u[j];
#pragma unroll
      for (int k2 = 0; k2 < 4; k2++) {
        const int p = 4 * i + k2;
        brow[p * 64 + (ci ^ ((p & 7) << 3))] = f2bf(w4.f[k2]);
      }
    }
  }
  __syncthreads();                                           // THE one barrier:
                                                             // B visible, A0 landed
#pragma unroll
  for (int kh = 0; kh < 3; kh++)
#pragma unroll
    for (int kw = 0; kw < 3; kw++) {
      const int khw = kh * 3 + kw;
      const unsigned short* bcur = Bs + (wn + kh) * 4608;
      short8 a[2][4], bf[2][4];
#pragma unroll
      for (int half = 0; half < 2; half++) {
        const int colb = half * 32 + q * 8;
#pragma unroll
        for (int mt = 0; mt < 4; mt++)
          a[half][mt] =
              *(const short8*)(Asw + (mt * 16 + m) * 64 + (colb ^ ((m & 7) << 3)));
#pragma unroll
        for (int nt = 0; nt < 4; nt++)
          bf[half][nt] = *(const short8*)(bcur + (nt * 16 + m + kw) * 64 +
                                          (colb ^ (((m + kw) & 7) << 3)));
      }
      asm volatile("s_waitcnt lgkmcnt(0)" ::: "memory");     // all reads in regs;
      if (khw < 8) stageA(khw + 1);                          // safe to overwrite Asw
#pragma unroll
      for (int half = 0; half < 2; half++)
#pragma unroll
        for (int mt = 0; mt < 4; mt++)
#pragma unroll
          for (int nt = 0; nt < 4; nt++)
            acc[mt][nt] = __builtin_amdgcn_mfma_f32_16x16x32_bf16(
                a[half][mt], bf[half][nt], acc[mt][nt], 0, 0, 0);
      if (khw < 8)
        asm volatile("s_waitcnt vmcnt(0)" ::: "memory");     // own stage landed
    }

  // epilogue: bias + fast tanh-GELU (y*sigmoid(2u)) + masked pool
  // D layout: col n = wn*64 + nt*16 + (lane&15) -> w' = nt*16+m; row co = q*4+r
  const float inv_area = 1.0f / (126.0f * 126.0f);
  float* orow = out + b * 128;
#pragma unroll
  for (int mt = 0; mt < 4; mt++)
#pragma unroll
    for (int r2 = 0; r2 < 4; r2++) {
      const int co = wm * 64 + mt * 16 + q * 4 + r2;
      const float bv = bias[co];
      float s = 0.f;
#pragma unroll
      for (int nt = 0; nt < 4; nt++) {
        float y = acc[mt][nt][r2] + bv;
        float u = GK0 * (y + GC1 * y * y * y);
        float e = __expf(-2.0f * u);
        float g = y * __builtin_amdgcn_rcpf(1.0f + e);       // == 0.5y(1+tanh u)
        if (w0 + nt * 16 + m < 126) s += g;                  // mask padded w'
      }
#pragma unroll
      for (int d = 1; d < 16; d <<= 1) s += __shfl_xor(s, d, 64);
      if (m == 0) atomicAdd(&orow[co], s * inv_area);
    }
}

extern "C" void kernel_launch(void* const* d_in, const int* in_sizes, int n_in,
                              void* d_out, int out_size, void* d_ws, size_t ws_size,
                              hipStream_t stream) {
  const float* x    = (const float*)d_in[0];
  const float* w    = (const float*)d_in[1];
  const float* bias = (const float*)d_in[2];
  float* out = (float*)d_out;

  unsigned short* wbuf = (unsigned short*)d_ws;              // 144 KB weights only
  if (ws_size < (size_t)9 * 128 * 64 * 2 + 4096) return;

  k_wt<<<288, 256, 0, stream>>>(w, wbuf, out);
  k_conv<<<dim3(2, 63, 32), 256, 0, stream>>>(x, wbuf, bias, out);
}